// Round 5
// baseline (327.245 us; speedup 1.0000x reference)
//
#include <hip/hip_runtime.h>
#include <math.h>

#define SQRT3F 1.7320508075688772f

typedef _Float16 half8 __attribute__((ext_vector_type(8)));
typedef _Float16 half4 __attribute__((ext_vector_type(4)));
typedef float    f32x4 __attribute__((ext_vector_type(4)));

// ---------------------------------------------------------------------------
// Round-5: DIAGNOSTIC round #2 (round-4's probe was spoiled by L2 absorbing
// same-address rewrites; main ~= 63-66 us by subtraction, ~3x its 21 us
// write floor, cause still unknown).
//
// Two probes, each = the REAL main body looped 3x with an iteration-salted
// row-band permutation (bijective per iter -> every pass writes the full
// 134 MB at DIFFERENT tiles per block -> L2 cannot absorb; operand loads
// follow the salted band). Each probe ~= 3x main ~= 190 us -> forced into
// rocprof top-5 WITH full counters (hbm_gbps / FETCH / VALUBusy /
// Occupancy / VGPR) for our exact kernel shape. Probe B = identical + NT
// stores (tests "write stream evicts the 3 MB operand set from L2/L3").
// Real main runs last, overwrites everything -> output unchanged.
//
// Pre-committed reads:
//   A write-BW ~2 TB/s            -> scatter-write locality wall -> remap.
//   VALUBusy > 60% / VGPR >= 128  -> epilogue VALU / spill bound.
//   FETCH large or B << A         -> L3/L2 eviction -> ship NT stores.
//   all pipes low, write ~6 TB/s  -> latency-bound -> occupancy/ILP.
// ---------------------------------------------------------------------------

__global__ __launch_bounds__(256)
void matern_prep_kernel(const float* __restrict__ X, const float* __restrict__ Z,
                        _Float16* __restrict__ Xh, _Float16* __restrict__ Xl,
                        _Float16* __restrict__ Zh, _Float16* __restrict__ Zl,
                        float* __restrict__ x2, float* __restrict__ z2,
                        int N, int M) {
    const int idx    = blockIdx.x * 256 + threadIdx.x;
    const int cellsX = N * 8;
    const int cells  = (N + M) * 8;

    if (idx < cells) {
        const float* src; _Float16 *dh, *dl; int c = idx;
        if (c < cellsX) { src = X; dh = Xh; dl = Xl; }
        else            { c -= cellsX; src = Z; dh = Zh; dl = Zl; }
        const int R   = c >> 7;
        const int w_  = c & 127;
        const int kc  = w_ >> 6;
        const int q   = (w_ >> 4) & 3;
        const int lm  = w_ & 15;
        const int row = R * 16 + lm;
        const int k   = kc * 32 + q * 8;
        const float* p = src + (size_t)row * 64 + k;
        const float4 a = *(const float4*)p;
        const float4 b = *(const float4*)(p + 4);
        const float in[8] = { a.x, a.y, a.z, a.w, b.x, b.y, b.z, b.w };
        half8 hv, lv;
        #pragma unroll
        for (int j = 0; j < 8; ++j) {
            _Float16 h = (_Float16)in[j];
            hv[j] = h;
            lv[j] = (_Float16)(in[j] - (float)h);
        }
        *(half8*)(dh + (size_t)c * 8) = hv;
        *(half8*)(dl + (size_t)c * 8) = lv;
    } else {
        int f = idx - cells;
        const int totX = N * 16;
        const int tot  = (N + M) * 16;
        if (f >= tot) return;
        const float* src; float* nrm;
        if (f < totX) { src = X; nrm = x2; }
        else          { f -= totX; src = Z; nrm = z2; }
        const float4 v = *(const float4*)(src + (size_t)f * 4);
        float ssq = v.x * v.x + v.y * v.y + v.z * v.z + v.w * v.w;
        ssq += __shfl_xor(ssq, 1, 16);
        ssq += __shfl_xor(ssq, 2, 16);
        ssq += __shfl_xor(ssq, 4, 16);
        ssq += __shfl_xor(ssq, 8, 16);
        if ((threadIdx.x & 15) == 0) nrm[f >> 4] = ssq;
    }
}

// Shared body: computes one 128x64 block tile for row-band `by`, col-tile
// `bx`, exactly as the real main. NT selects nontemporal stores.
template <int NT>
__device__ __forceinline__
void matern_tile(const _Float16* __restrict__ Xh, const _Float16* __restrict__ Xl,
                 const _Float16* __restrict__ Zh, const _Float16* __restrict__ Zl,
                 const float* __restrict__ x2, const float* __restrict__ z2,
                 float s2, float fac, float* __restrict__ out, int M,
                 int bx, int by, int w, int lane, float* wbuf) {
    const int wr   = w >> 1;
    const int wc   = w & 1;
    const int m0   = by * 128 + wr * 64;
    const int n0   = bx * 64  + wc * 32;
    const int Rb0  = by * 8 + wr * 4;
    const int Cb0  = bx * 4 + wc * 2;
    const int lm   = lane & 15;
    const int q    = lane >> 4;

    f32x4 acc[4][2];
    #pragma unroll
    for (int a = 0; a < 4; ++a)
        #pragma unroll
        for (int b = 0; b < 2; ++b)
            acc[a][b] = (f32x4){0.f, 0.f, 0.f, 0.f};

    #pragma unroll
    for (int kc = 0; kc < 2; ++kc) {
        half8 ah[4], al[4], bh[2], bl[2];
        #pragma unroll
        for (int mt = 0; mt < 4; ++mt) {
            const size_t off = ((size_t)(Rb0 + mt) * 2 + kc) * 512 + (size_t)lane * 8;
            ah[mt] = *(const half8*)(Xh + off);
            al[mt] = *(const half8*)(Xl + off);
        }
        #pragma unroll
        for (int nt = 0; nt < 2; ++nt) {
            const size_t off = ((size_t)(Cb0 + nt) * 2 + kc) * 512 + (size_t)lane * 8;
            bh[nt] = *(const half8*)(Zh + off);
            bl[nt] = *(const half8*)(Zl + off);
        }
        #pragma unroll
        for (int mt = 0; mt < 4; ++mt)
            #pragma unroll
            for (int nt = 0; nt < 2; ++nt) {
                acc[mt][nt] = __builtin_amdgcn_mfma_f32_16x16x32_f16(ah[mt], bh[nt], acc[mt][nt], 0, 0, 0);
                acc[mt][nt] = __builtin_amdgcn_mfma_f32_16x16x32_f16(ah[mt], bl[nt], acc[mt][nt], 0, 0, 0);
                acc[mt][nt] = __builtin_amdgcn_mfma_f32_16x16x32_f16(al[mt], bh[nt], acc[mt][nt], 0, 0, 0);
            }
    }

    #pragma unroll
    for (int mt = 0; mt < 4; ++mt) {
        const int rl0 = mt * 16 + q * 4;
        const f32x4 xr = *(const f32x4*)(x2 + m0 + rl0);
        #pragma unroll
        for (int nt = 0; nt < 2; ++nt) {
            const int cl = nt * 16 + lm;
            const float zc = z2[n0 + cl];
            #pragma unroll
            for (int r = 0; r < 4; ++r) {
                float sq  = xr[r] + zc - 2.0f * acc[mt][nt][r];
                float d   = __builtin_amdgcn_sqrtf(fmaxf(sq, 1e-12f));
                float val = fac * d;
                wbuf[(rl0 + r) * 36 + cl] = s2 * (1.0f + val) * __expf(-val);
            }
        }
    }

    const int rrow = lane >> 3;
    const int cg   = (lane & 7) << 2;
    #pragma unroll
    for (int rr = 0; rr < 8; ++rr) {
        const int rl = rr * 8 + rrow;
        const f32x4 v = *(const f32x4*)&wbuf[rl * 36 + cg];
        float* op = out + (size_t)(m0 + rl) * (size_t)M + n0 + cg;
        if (NT) {
            __builtin_nontemporal_store(v[0], op);
            __builtin_nontemporal_store(v[1], op + 1);
            __builtin_nontemporal_store(v[2], op + 2);
            __builtin_nontemporal_store(v[3], op + 3);
        } else {
            *(f32x4*)op = v;
        }
    }
}

template <int NT>
__global__ __launch_bounds__(256, 4)
void matern_probe3x(const _Float16* __restrict__ Xh, const _Float16* __restrict__ Xl,
                    const _Float16* __restrict__ Zh, const _Float16* __restrict__ Zl,
                    const float* __restrict__ x2, const float* __restrict__ z2,
                    const float* __restrict__ sigma, const float* __restrict__ lengthscale,
                    float* __restrict__ out, int M) {
    __shared__ float buf[4][64][36];
    const int t    = threadIdx.x;
    const int lane = t & 63;
    const int w    = t >> 6;
    const float s   = sigma[0];
    const float l   = lengthscale[0];
    const float fac = SQRT3F / l;
    const float s2  = s * s;
    for (int it = 0; it < 3; ++it) {
        // bijective band permutation per iteration: full 134 MB written each
        // pass, different tile per block -> L2 cannot absorb rewrites.
        const int by = (blockIdx.y + 21 * it) & 63;
        matern_tile<NT>(Xh, Xl, Zh, Zl, x2, z2, s2, fac, out, M,
                        blockIdx.x, by, w, lane, &buf[w][0][0]);
        __asm__ volatile("" ::: "memory");
    }
}

__global__ __launch_bounds__(256, 4)
void matern_main_kernel(const _Float16* __restrict__ Xh, const _Float16* __restrict__ Xl,
                        const _Float16* __restrict__ Zh, const _Float16* __restrict__ Zl,
                        const float* __restrict__ x2, const float* __restrict__ z2,
                        const float* __restrict__ sigma, const float* __restrict__ lengthscale,
                        float* __restrict__ out, int M) {
    __shared__ float buf[4][64][36];
    const int t    = threadIdx.x;
    const float s   = sigma[0];
    const float l   = lengthscale[0];
    matern_tile<0>(Xh, Xl, Zh, Zl, x2, z2, s * s, SQRT3F / l, out, M,
                   blockIdx.x, blockIdx.y, t >> 6, t & 63, &buf[t >> 6][0][0]);
}

extern "C" void kernel_launch(void* const* d_in, const int* in_sizes, int n_in,
                              void* d_out, int out_size, void* d_ws, size_t ws_size,
                              hipStream_t stream) {
    (void)n_in; (void)out_size; (void)ws_size;
    const float* X   = (const float*)d_in[0];
    const float* Z   = (const float*)d_in[1];
    const float* sig = (const float*)d_in[2];
    const float* len = (const float*)d_in[3];
    float* out = (float*)d_out;

    const int D = 64;
    const int N = in_sizes[0] / D;   // 8192
    const int M = in_sizes[1] / D;   // 4096

    char* ws = (char*)d_ws;
    size_t o = 0;
    auto take = [&](size_t bytes) { char* p = ws + o; o += (bytes + 255) & ~(size_t)255; return p; };
    _Float16* Xh = (_Float16*)take((size_t)N * D * sizeof(_Float16));
    _Float16* Xl = (_Float16*)take((size_t)N * D * sizeof(_Float16));
    _Float16* Zh = (_Float16*)take((size_t)M * D * sizeof(_Float16));
    _Float16* Zl = (_Float16*)take((size_t)M * D * sizeof(_Float16));
    float*    x2 = (float*)take((size_t)N * sizeof(float));
    float*    z2 = (float*)take((size_t)M * sizeof(float));

    const int cells = (N + M) * 8;
    const int tot   = cells + (N + M) * 16;
    matern_prep_kernel<<<(tot + 255) / 256, 256, 0, stream>>>(X, Z, Xh, Xl, Zh, Zl, x2, z2, N, M);

    dim3 grid(M / 64, N / 128);      // 4096 blocks, 4 waves each

    // Probe A: main x3, salted bands, regular stores -> full PMC row.
    matern_probe3x<0><<<grid, 256, 0, stream>>>(Xh, Xl, Zh, Zl, x2, z2, sig, len, out, M);
    // Probe B: identical + nontemporal stores -> isolates L2/L3 eviction.
    matern_probe3x<1><<<grid, 256, 0, stream>>>(Xh, Xl, Zh, Zl, x2, z2, sig, len, out, M);
    // Real main (overwrites everything -> output correctness unchanged).
    matern_main_kernel<<<grid, 256, 0, stream>>>(Xh, Xl, Zh, Zl, x2, z2, sig, len, out, M);
}

// Round 6
// 190.773 us; speedup vs baseline: 1.7154x; 1.7154x over previous
//
#include <hip/hip_runtime.h>
#include <math.h>

#define SQRT3F 1.7320508075688772f

typedef _Float16 half8 __attribute__((ext_vector_type(8)));
typedef _Float16 half4 __attribute__((ext_vector_type(4)));
typedef float    f32x4 __attribute__((ext_vector_type(4)));

// ---------------------------------------------------------------------------
// Round-6: probe-driven fixes (round-5 measured the real main at ~32.5 us,
// 4.3 TB/s regular stores vs 5.2 TB/s NT, occupancy 39%, VGPR 64, no pipe
// saturated).
//   1. NT stores, vectorized: __builtin_nontemporal_store of f32x4 on the
//      LDS-transposed full-line pattern (output is write-once; bypassing L2
//      avoids write-allocate/dirty-eviction and protects the 3 MB operand
//      set).  Probe B measured +20% write BW for this.
//   2. Occupancy 2x: LDS slab halved to [4][32][36] = 18 KB (epilogue runs
//      in two 32-row halves; wave-private LDS ops are in-order and alias ->
//      no barrier), __launch_bounds__(256, 8) -> 8 blocks/CU = 32 waves/CU
//      (VGPR 64 fits).  More waves hide epilogue VALU + store latency.
// Prep (fragment-ordered convert + norms, once per element) unchanged.
// ---------------------------------------------------------------------------

__global__ __launch_bounds__(256)
void matern_prep_kernel(const float* __restrict__ X, const float* __restrict__ Z,
                        _Float16* __restrict__ Xh, _Float16* __restrict__ Xl,
                        _Float16* __restrict__ Zh, _Float16* __restrict__ Zl,
                        float* __restrict__ x2, float* __restrict__ z2,
                        int N, int M) {
    const int idx    = blockIdx.x * 256 + threadIdx.x;
    const int cellsX = N * 8;
    const int cells  = (N + M) * 8;

    if (idx < cells) {
        const float* src; _Float16 *dh, *dl; int c = idx;
        if (c < cellsX) { src = X; dh = Xh; dl = Xl; }
        else            { c -= cellsX; src = Z; dh = Zh; dl = Zl; }
        const int R   = c >> 7;
        const int w_  = c & 127;
        const int kc  = w_ >> 6;
        const int q   = (w_ >> 4) & 3;
        const int lm  = w_ & 15;
        const int row = R * 16 + lm;
        const int k   = kc * 32 + q * 8;
        const float* p = src + (size_t)row * 64 + k;
        const float4 a = *(const float4*)p;
        const float4 b = *(const float4*)(p + 4);
        const float in[8] = { a.x, a.y, a.z, a.w, b.x, b.y, b.z, b.w };
        half8 hv, lv;
        #pragma unroll
        for (int j = 0; j < 8; ++j) {
            _Float16 h = (_Float16)in[j];
            hv[j] = h;
            lv[j] = (_Float16)(in[j] - (float)h);
        }
        *(half8*)(dh + (size_t)c * 8) = hv;
        *(half8*)(dl + (size_t)c * 8) = lv;
    } else {
        int f = idx - cells;
        const int totX = N * 16;
        const int tot  = (N + M) * 16;
        if (f >= tot) return;
        const float* src; float* nrm;
        if (f < totX) { src = X; nrm = x2; }
        else          { f -= totX; src = Z; nrm = z2; }
        const float4 v = *(const float4*)(src + (size_t)f * 4);
        float ssq = v.x * v.x + v.y * v.y + v.z * v.z + v.w * v.w;
        ssq += __shfl_xor(ssq, 1, 16);
        ssq += __shfl_xor(ssq, 2, 16);
        ssq += __shfl_xor(ssq, 4, 16);
        ssq += __shfl_xor(ssq, 8, 16);
        if ((threadIdx.x & 15) == 0) nrm[f >> 4] = ssq;
    }
}

__global__ __launch_bounds__(256, 8)
void matern_main_kernel(const _Float16* __restrict__ Xh, const _Float16* __restrict__ Xl,
                        const _Float16* __restrict__ Zh, const _Float16* __restrict__ Zl,
                        const float* __restrict__ x2, const float* __restrict__ z2,
                        const float* __restrict__ sigma, const float* __restrict__ lengthscale,
                        float* __restrict__ out, int M) {
    // wave-private 32-row half-tile staging: 18 KB -> 8 blocks/CU
    __shared__ float buf[4][32][36];

    const int t    = threadIdx.x;
    const int lane = t & 63;
    const int w    = t >> 6;
    const int wr   = w >> 1;
    const int wc   = w & 1;
    const int m0   = blockIdx.y * 128 + wr * 64;
    const int n0   = blockIdx.x * 64  + wc * 32;
    const int Rb0  = (blockIdx.y * 8) + wr * 4;
    const int Cb0  = (blockIdx.x * 4) + wc * 2;
    const int lm   = lane & 15;
    const int q    = lane >> 4;

    f32x4 acc[4][2];
    #pragma unroll
    for (int a = 0; a < 4; ++a)
        #pragma unroll
        for (int b = 0; b < 2; ++b)
            acc[a][b] = (f32x4){0.f, 0.f, 0.f, 0.f};

    #pragma unroll
    for (int kc = 0; kc < 2; ++kc) {
        half8 ah[4], al[4], bh[2], bl[2];
        #pragma unroll
        for (int mt = 0; mt < 4; ++mt) {
            const size_t off = ((size_t)(Rb0 + mt) * 2 + kc) * 512 + (size_t)lane * 8;
            ah[mt] = *(const half8*)(Xh + off);
            al[mt] = *(const half8*)(Xl + off);
        }
        #pragma unroll
        for (int nt = 0; nt < 2; ++nt) {
            const size_t off = ((size_t)(Cb0 + nt) * 2 + kc) * 512 + (size_t)lane * 8;
            bh[nt] = *(const half8*)(Zh + off);
            bl[nt] = *(const half8*)(Zl + off);
        }
        #pragma unroll
        for (int mt = 0; mt < 4; ++mt)
            #pragma unroll
            for (int nt = 0; nt < 2; ++nt) {
                acc[mt][nt] = __builtin_amdgcn_mfma_f32_16x16x32_f16(ah[mt], bh[nt], acc[mt][nt], 0, 0, 0);
                acc[mt][nt] = __builtin_amdgcn_mfma_f32_16x16x32_f16(ah[mt], bl[nt], acc[mt][nt], 0, 0, 0);
                acc[mt][nt] = __builtin_amdgcn_mfma_f32_16x16x32_f16(al[mt], bh[nt], acc[mt][nt], 0, 0, 0);
            }
    }

    const float s   = sigma[0];
    const float l   = lengthscale[0];
    const float fac = SQRT3F / l;
    const float s2  = s * s;

    float* wbuf = &buf[w][0][0];
    const int rrow = lane >> 3;
    const int cg   = (lane & 7) << 2;

    // Two 32-row halves through the same LDS slab. Wave-private + in-order
    // per-wave LDS ops + identical (aliasing) addresses across halves ->
    // no barrier needed; compiler cannot reorder writes above the reads.
    #pragma unroll
    for (int half = 0; half < 2; ++half) {
        #pragma unroll
        for (int mtl = 0; mtl < 2; ++mtl) {
            const int mt  = half * 2 + mtl;
            const int rl0 = mtl * 16 + q * 4;            // LDS-local row base
            const f32x4 xr = *(const f32x4*)(x2 + m0 + mt * 16 + q * 4);
            #pragma unroll
            for (int nt = 0; nt < 2; ++nt) {
                const int cl = nt * 16 + lm;
                const float zc = z2[n0 + cl];
                #pragma unroll
                for (int r = 0; r < 4; ++r) {
                    float sq  = xr[r] + zc - 2.0f * acc[mt][nt][r];
                    float d   = __builtin_amdgcn_sqrtf(fmaxf(sq, 1e-12f));
                    float val = fac * d;
                    wbuf[(rl0 + r) * 36 + cl] = s2 * (1.0f + val) * __expf(-val);
                }
            }
        }
        #pragma unroll
        for (int rr = 0; rr < 4; ++rr) {
            const int rl = rr * 8 + rrow;                // 0..31 within half
            const f32x4 v = *(const f32x4*)&wbuf[rl * 36 + cg];
            float* op = out + (size_t)(m0 + half * 32 + rl) * (size_t)M + n0 + cg;
            __builtin_nontemporal_store(v, (f32x4*)op);  // full-line NT dwordx4
        }
    }
}

extern "C" void kernel_launch(void* const* d_in, const int* in_sizes, int n_in,
                              void* d_out, int out_size, void* d_ws, size_t ws_size,
                              hipStream_t stream) {
    (void)n_in; (void)out_size; (void)ws_size;
    const float* X   = (const float*)d_in[0];
    const float* Z   = (const float*)d_in[1];
    const float* sig = (const float*)d_in[2];
    const float* len = (const float*)d_in[3];
    float* out = (float*)d_out;

    const int D = 64;
    const int N = in_sizes[0] / D;   // 8192
    const int M = in_sizes[1] / D;   // 4096

    char* ws = (char*)d_ws;
    size_t o = 0;
    auto take = [&](size_t bytes) { char* p = ws + o; o += (bytes + 255) & ~(size_t)255; return p; };
    _Float16* Xh = (_Float16*)take((size_t)N * D * sizeof(_Float16));
    _Float16* Xl = (_Float16*)take((size_t)N * D * sizeof(_Float16));
    _Float16* Zh = (_Float16*)take((size_t)M * D * sizeof(_Float16));
    _Float16* Zl = (_Float16*)take((size_t)M * D * sizeof(_Float16));
    float*    x2 = (float*)take((size_t)N * sizeof(float));
    float*    z2 = (float*)take((size_t)M * sizeof(float));

    const int cells = (N + M) * 8;
    const int tot   = cells + (N + M) * 16;
    matern_prep_kernel<<<(tot + 255) / 256, 256, 0, stream>>>(X, Z, Xh, Xl, Zh, Zl, x2, z2, N, M);

    dim3 grid(M / 64, N / 128);      // 4096 blocks, 4 waves each
    matern_main_kernel<<<grid, 256, 0, stream>>>(Xh, Xl, Zh, Zl, x2, z2, sig, len, out, M);
}

// Round 7
// 155.667 us; speedup vs baseline: 2.1022x; 1.2255x over previous
//
#include <hip/hip_runtime.h>
#include <math.h>

#define SQRT3F 1.7320508075688772f

typedef _Float16 half8 __attribute__((ext_vector_type(8)));
typedef _Float16 half4 __attribute__((ext_vector_type(4)));
typedef float    f32x4 __attribute__((ext_vector_type(4)));

// ---------------------------------------------------------------------------
// Round-7: round-3 known-good structure (fragment-ordered prepass,
// barrier-free main, per-wave LDS transpose, full-line stores) + ONE change:
// scalar nontemporal stores, exactly as round-5's probe B measured at the
// write roofline (~6.5 TB/s vs 4.3 TB/s regular -- L2 write-allocate/dirty
// eviction on a never-re-read 134 MB stream).
//
// Round-6's regression (152->191) bundled NT-vector stores with a
// (256,8)/halved-slab occupancy change; suspected VGPR squeeze (was exactly
// 64) -> spills. All of that is reverted: launch_bounds(256,4), 36 KB slab,
// single-pass epilogue, VGPR 64.
// ---------------------------------------------------------------------------

__global__ __launch_bounds__(256)
void matern_prep_kernel(const float* __restrict__ X, const float* __restrict__ Z,
                        _Float16* __restrict__ Xh, _Float16* __restrict__ Xl,
                        _Float16* __restrict__ Zh, _Float16* __restrict__ Zl,
                        float* __restrict__ x2, float* __restrict__ z2,
                        int N, int M) {
    const int idx    = blockIdx.x * 256 + threadIdx.x;
    const int cellsX = N * 8;
    const int cells  = (N + M) * 8;

    if (idx < cells) {
        const float* src; _Float16 *dh, *dl; int c = idx;
        if (c < cellsX) { src = X; dh = Xh; dl = Xl; }
        else            { c -= cellsX; src = Z; dh = Zh; dl = Zl; }
        const int R   = c >> 7;
        const int w_  = c & 127;
        const int kc  = w_ >> 6;
        const int q   = (w_ >> 4) & 3;
        const int lm  = w_ & 15;
        const int row = R * 16 + lm;
        const int k   = kc * 32 + q * 8;
        const float* p = src + (size_t)row * 64 + k;
        const float4 a = *(const float4*)p;
        const float4 b = *(const float4*)(p + 4);
        const float in[8] = { a.x, a.y, a.z, a.w, b.x, b.y, b.z, b.w };
        half8 hv, lv;
        #pragma unroll
        for (int j = 0; j < 8; ++j) {
            _Float16 h = (_Float16)in[j];
            hv[j] = h;
            lv[j] = (_Float16)(in[j] - (float)h);
        }
        *(half8*)(dh + (size_t)c * 8) = hv;
        *(half8*)(dl + (size_t)c * 8) = lv;
    } else {
        int f = idx - cells;
        const int totX = N * 16;
        const int tot  = (N + M) * 16;
        if (f >= tot) return;
        const float* src; float* nrm;
        if (f < totX) { src = X; nrm = x2; }
        else          { f -= totX; src = Z; nrm = z2; }
        const float4 v = *(const float4*)(src + (size_t)f * 4);
        float ssq = v.x * v.x + v.y * v.y + v.z * v.z + v.w * v.w;
        ssq += __shfl_xor(ssq, 1, 16);
        ssq += __shfl_xor(ssq, 2, 16);
        ssq += __shfl_xor(ssq, 4, 16);
        ssq += __shfl_xor(ssq, 8, 16);
        if ((threadIdx.x & 15) == 0) nrm[f >> 4] = ssq;
    }
}

__global__ __launch_bounds__(256, 4)
void matern_main_kernel(const _Float16* __restrict__ Xh, const _Float16* __restrict__ Xl,
                        const _Float16* __restrict__ Zh, const _Float16* __restrict__ Zl,
                        const float* __restrict__ x2, const float* __restrict__ z2,
                        const float* __restrict__ sigma, const float* __restrict__ lengthscale,
                        float* __restrict__ out, int M) {
    __shared__ float buf[4][64][36];

    const int t    = threadIdx.x;
    const int lane = t & 63;
    const int w    = t >> 6;
    const int wr   = w >> 1;
    const int wc   = w & 1;
    const int m0   = blockIdx.y * 128 + wr * 64;
    const int n0   = blockIdx.x * 64  + wc * 32;
    const int Rb0  = (blockIdx.y * 8) + wr * 4;
    const int Cb0  = (blockIdx.x * 4) + wc * 2;
    const int lm   = lane & 15;
    const int q    = lane >> 4;

    f32x4 acc[4][2];
    #pragma unroll
    for (int a = 0; a < 4; ++a)
        #pragma unroll
        for (int b = 0; b < 2; ++b)
            acc[a][b] = (f32x4){0.f, 0.f, 0.f, 0.f};

    #pragma unroll
    for (int kc = 0; kc < 2; ++kc) {
        half8 ah[4], al[4], bh[2], bl[2];
        #pragma unroll
        for (int mt = 0; mt < 4; ++mt) {
            const size_t off = ((size_t)(Rb0 + mt) * 2 + kc) * 512 + (size_t)lane * 8;
            ah[mt] = *(const half8*)(Xh + off);
            al[mt] = *(const half8*)(Xl + off);
        }
        #pragma unroll
        for (int nt = 0; nt < 2; ++nt) {
            const size_t off = ((size_t)(Cb0 + nt) * 2 + kc) * 512 + (size_t)lane * 8;
            bh[nt] = *(const half8*)(Zh + off);
            bl[nt] = *(const half8*)(Zl + off);
        }
        #pragma unroll
        for (int mt = 0; mt < 4; ++mt)
            #pragma unroll
            for (int nt = 0; nt < 2; ++nt) {
                acc[mt][nt] = __builtin_amdgcn_mfma_f32_16x16x32_f16(ah[mt], bh[nt], acc[mt][nt], 0, 0, 0);
                acc[mt][nt] = __builtin_amdgcn_mfma_f32_16x16x32_f16(ah[mt], bl[nt], acc[mt][nt], 0, 0, 0);
                acc[mt][nt] = __builtin_amdgcn_mfma_f32_16x16x32_f16(al[mt], bh[nt], acc[mt][nt], 0, 0, 0);
            }
    }

    const float s   = sigma[0];
    const float l   = lengthscale[0];
    const float fac = SQRT3F / l;
    const float s2  = s * s;

    float* wbuf = &buf[w][0][0];

    #pragma unroll
    for (int mt = 0; mt < 4; ++mt) {
        const int rl0 = mt * 16 + q * 4;
        const f32x4 xr = *(const f32x4*)(x2 + m0 + rl0);
        #pragma unroll
        for (int nt = 0; nt < 2; ++nt) {
            const int cl = nt * 16 + lm;
            const float zc = z2[n0 + cl];
            #pragma unroll
            for (int r = 0; r < 4; ++r) {
                float sq  = xr[r] + zc - 2.0f * acc[mt][nt][r];
                float d   = __builtin_amdgcn_sqrtf(fmaxf(sq, 1e-12f));
                float val = fac * d;
                wbuf[(rl0 + r) * 36 + cl] = s2 * (1.0f + val) * __expf(-val);
            }
        }
    }

    // transpose read-back; full-line pattern; SCALAR NT stores (probe-B form)
    const int rrow = lane >> 3;
    const int cg   = (lane & 7) << 2;
    #pragma unroll
    for (int rr = 0; rr < 8; ++rr) {
        const int rl = rr * 8 + rrow;
        const f32x4 v = *(const f32x4*)&wbuf[rl * 36 + cg];
        float* op = out + (size_t)(m0 + rl) * (size_t)M + n0 + cg;
        __builtin_nontemporal_store(v[0], op);
        __builtin_nontemporal_store(v[1], op + 1);
        __builtin_nontemporal_store(v[2], op + 2);
        __builtin_nontemporal_store(v[3], op + 3);
    }
}

extern "C" void kernel_launch(void* const* d_in, const int* in_sizes, int n_in,
                              void* d_out, int out_size, void* d_ws, size_t ws_size,
                              hipStream_t stream) {
    (void)n_in; (void)out_size; (void)ws_size;
    const float* X   = (const float*)d_in[0];
    const float* Z   = (const float*)d_in[1];
    const float* sig = (const float*)d_in[2];
    const float* len = (const float*)d_in[3];
    float* out = (float*)d_out;

    const int D = 64;
    const int N = in_sizes[0] / D;   // 8192
    const int M = in_sizes[1] / D;   // 4096

    char* ws = (char*)d_ws;
    size_t o = 0;
    auto take = [&](size_t bytes) { char* p = ws + o; o += (bytes + 255) & ~(size_t)255; return p; };
    _Float16* Xh = (_Float16*)take((size_t)N * D * sizeof(_Float16));
    _Float16* Xl = (_Float16*)take((size_t)N * D * sizeof(_Float16));
    _Float16* Zh = (_Float16*)take((size_t)M * D * sizeof(_Float16));
    _Float16* Zl = (_Float16*)take((size_t)M * D * sizeof(_Float16));
    float*    x2 = (float*)take((size_t)N * sizeof(float));
    float*    z2 = (float*)take((size_t)M * sizeof(float));

    const int cells = (N + M) * 8;
    const int tot   = cells + (N + M) * 16;
    matern_prep_kernel<<<(tot + 255) / 256, 256, 0, stream>>>(X, Z, Xh, Xl, Zh, Zl, x2, z2, N, M);

    dim3 grid(M / 64, N / 128);      // 4096 blocks, 4 waves each
    matern_main_kernel<<<grid, 256, 0, stream>>>(Xh, Xl, Zh, Zl, x2, z2, sig, len, out, M);
}

// Round 8
// 150.058 us; speedup vs baseline: 2.1808x; 1.0374x over previous
//
#include <hip/hip_runtime.h>
#include <math.h>

#define SQRT3F 1.7320508075688772f

typedef _Float16 half8 __attribute__((ext_vector_type(8)));
typedef _Float16 half4 __attribute__((ext_vector_type(4)));
typedef float    f32x4 __attribute__((ext_vector_type(4)));

// ---------------------------------------------------------------------------
// Round-8: REVERT to the session's measured-best kernel (round-2, 151.0 us).
//
// Final structure:
//   Prepass: f32 -> (hi,lo) f16 split in MFMA FRAGMENT ORDER (each operand
//   load in main = ONE contiguous 1 KB wave transaction), + row norms.
//   Conversion/norms run once per element (the round-0 baseline redid them
//   32-64x inside every output tile behind a block-wide barrier).
//
//   Main: no LDS, no __syncthreads. Operands (~3 MB) L2-resident. 48 MFMAs
//   (f16 hi/lo 3-term split for fp32 accuracy), fused Matern-3/2 epilogue,
//   direct MFMA-layout f32x4 stores.
//
// Session findings (rounds 3-7, all within-harness-noise neutral):
//   store form {direct vector, LDS-transposed full-line, nontemporal} --
//   equivalent single-pass; occupancy 16 vs ~32 waves/CU -- equivalent;
//   probe-measured main ~= 32.5 us vs ~28-30 us composed floor
//   (write 21 + VALU 10-14 + L2 reads 11, well-overlapped). Remaining
//   upside ~2% of total, below noise; total dominated by ~120 us fixed
//   harness cost (re-poison fill at 79-84% HBM peak).
// ---------------------------------------------------------------------------

__global__ __launch_bounds__(256)
void matern_prep_kernel(const float* __restrict__ X, const float* __restrict__ Z,
                        _Float16* __restrict__ Xh, _Float16* __restrict__ Xl,
                        _Float16* __restrict__ Zh, _Float16* __restrict__ Zl,
                        float* __restrict__ x2, float* __restrict__ z2,
                        int N, int M) {
    const int idx    = blockIdx.x * 256 + threadIdx.x;
    const int cellsX = N * 8;            // (N/16 rowblocks) * 128 cells
    const int cells  = (N + M) * 8;      // one cell = 8 halves (16 B) per array

    if (idx < cells) {
        // ---- fragment-order conversion: one 16B hi + 16B lo cell ----
        const float* src; _Float16 *dh, *dl; int c = idx;
        if (c < cellsX) { src = X; dh = Xh; dl = Xl; }
        else            { c -= cellsX; src = Z; dh = Zh; dl = Zl; }
        const int R   = c >> 7;          // 16-row block
        const int w_  = c & 127;
        const int kc  = w_ >> 6;         // K half (0..1)
        const int q   = (w_ >> 4) & 3;   // k quarter within half
        const int lm  = w_ & 15;         // row within block
        const int row = R * 16 + lm;
        const int k   = kc * 32 + q * 8;
        const float* p = src + (size_t)row * 64 + k;
        const float4 a = *(const float4*)p;
        const float4 b = *(const float4*)(p + 4);
        const float in[8] = { a.x, a.y, a.z, a.w, b.x, b.y, b.z, b.w };
        half8 hv, lv;
        #pragma unroll
        for (int j = 0; j < 8; ++j) {
            _Float16 h = (_Float16)in[j];
            hv[j] = h;
            lv[j] = (_Float16)(in[j] - (float)h);
        }
        *(half8*)(dh + (size_t)c * 8) = hv;
        *(half8*)(dl + (size_t)c * 8) = lv;
    } else {
        // ---- row squared norms: 16 consecutive threads per row ----
        int f = idx - cells;             // float4-chunk index
        const int totX = N * 16;
        const int tot  = (N + M) * 16;
        if (f >= tot) return;
        const float* src; float* nrm;
        if (f < totX) { src = X; nrm = x2; }
        else          { f -= totX; src = Z; nrm = z2; }
        const float4 v = *(const float4*)(src + (size_t)f * 4);
        float ssq = v.x * v.x + v.y * v.y + v.z * v.z + v.w * v.w;
        ssq += __shfl_xor(ssq, 1, 16);
        ssq += __shfl_xor(ssq, 2, 16);
        ssq += __shfl_xor(ssq, 4, 16);
        ssq += __shfl_xor(ssq, 8, 16);
        if ((threadIdx.x & 15) == 0) nrm[f >> 4] = ssq;
    }
}

__global__ __launch_bounds__(256, 4)
void matern_main_kernel(const _Float16* __restrict__ Xh, const _Float16* __restrict__ Xl,
                        const _Float16* __restrict__ Zh, const _Float16* __restrict__ Zl,
                        const float* __restrict__ x2, const float* __restrict__ z2,
                        const float* __restrict__ sigma, const float* __restrict__ lengthscale,
                        float* __restrict__ out, int M) {
    const int t    = threadIdx.x;
    const int lane = t & 63;
    const int w    = t >> 6;         // 0..3 waves
    const int wr   = w >> 1;         // 0..1
    const int wc   = w & 1;          // 0..1
    const int m0   = blockIdx.y * 128 + wr * 64;   // X rows owned by this wave
    const int n0   = blockIdx.x * 64  + wc * 32;   // Z rows (output cols)
    const int Rb0  = (blockIdx.y * 8) + wr * 4;    // X 16-row-block base
    const int Cb0  = (blockIdx.x * 4) + wc * 2;    // Z 16-row-block base
    const int lm   = lane & 15;
    const int q    = lane >> 4;

    f32x4 acc[4][2];
    #pragma unroll
    for (int a = 0; a < 4; ++a)
        #pragma unroll
        for (int b = 0; b < 2; ++b)
            acc[a][b] = (f32x4){0.f, 0.f, 0.f, 0.f};

    #pragma unroll
    for (int kc = 0; kc < 2; ++kc) {
        half8 ah[4], al[4], bh[2], bl[2];
        #pragma unroll
        for (int mt = 0; mt < 4; ++mt) {
            // one contiguous 1 KB wave load: lane reads base + lane*16B
            const size_t off = ((size_t)(Rb0 + mt) * 2 + kc) * 512 + (size_t)lane * 8;
            ah[mt] = *(const half8*)(Xh + off);
            al[mt] = *(const half8*)(Xl + off);
        }
        #pragma unroll
        for (int nt = 0; nt < 2; ++nt) {
            const size_t off = ((size_t)(Cb0 + nt) * 2 + kc) * 512 + (size_t)lane * 8;
            bh[nt] = *(const half8*)(Zh + off);
            bl[nt] = *(const half8*)(Zl + off);
        }
        #pragma unroll
        for (int mt = 0; mt < 4; ++mt)
            #pragma unroll
            for (int nt = 0; nt < 2; ++nt) {
                acc[mt][nt] = __builtin_amdgcn_mfma_f32_16x16x32_f16(ah[mt], bh[nt], acc[mt][nt], 0, 0, 0);
                acc[mt][nt] = __builtin_amdgcn_mfma_f32_16x16x32_f16(ah[mt], bl[nt], acc[mt][nt], 0, 0, 0);
                acc[mt][nt] = __builtin_amdgcn_mfma_f32_16x16x32_f16(al[mt], bh[nt], acc[mt][nt], 0, 0, 0);
            }
    }

    const float s   = sigma[0];
    const float l   = lengthscale[0];
    const float fac = SQRT3F / l;
    const float s2  = s * s;

    #pragma unroll
    for (int mt = 0; mt < 4; ++mt) {
        const int row0 = m0 + mt * 16 + q * 4;          // multiple of 4 -> f32x4 aligned
        const f32x4 xr = *(const f32x4*)(x2 + row0);
        #pragma unroll
        for (int nt = 0; nt < 2; ++nt) {
            const int col = n0 + nt * 16 + lm;
            const float zc = z2[col];
            float* op = out + (size_t)row0 * (size_t)M + col;
            #pragma unroll
            for (int r = 0; r < 4; ++r) {
                float sq  = xr[r] + zc - 2.0f * acc[mt][nt][r];
                float d   = __builtin_amdgcn_sqrtf(fmaxf(sq, 1e-12f));
                float val = fac * d;
                *op = s2 * (1.0f + val) * __expf(-val);
                op += M;
            }
        }
    }
}

extern "C" void kernel_launch(void* const* d_in, const int* in_sizes, int n_in,
                              void* d_out, int out_size, void* d_ws, size_t ws_size,
                              hipStream_t stream) {
    (void)n_in; (void)out_size; (void)ws_size;
    const float* X   = (const float*)d_in[0];
    const float* Z   = (const float*)d_in[1];
    const float* sig = (const float*)d_in[2];
    const float* len = (const float*)d_in[3];
    float* out = (float*)d_out;

    const int D = 64;
    const int N = in_sizes[0] / D;   // 8192
    const int M = in_sizes[1] / D;   // 4096

    // Workspace layout (256B-aligned slices; total ~3.1 MB).
    char* ws = (char*)d_ws;
    size_t o = 0;
    auto take = [&](size_t bytes) { char* p = ws + o; o += (bytes + 255) & ~(size_t)255; return p; };
    _Float16* Xh = (_Float16*)take((size_t)N * D * sizeof(_Float16));
    _Float16* Xl = (_Float16*)take((size_t)N * D * sizeof(_Float16));
    _Float16* Zh = (_Float16*)take((size_t)M * D * sizeof(_Float16));
    _Float16* Zl = (_Float16*)take((size_t)M * D * sizeof(_Float16));
    float*    x2 = (float*)take((size_t)N * sizeof(float));
    float*    z2 = (float*)take((size_t)M * sizeof(float));

    // prep grid covers fragment cells + norm chunks
    const int cells = (N + M) * 8;
    const int tot   = cells + (N + M) * 16;
    matern_prep_kernel<<<(tot + 255) / 256, 256, 0, stream>>>(X, Z, Xh, Xl, Zh, Zl, x2, z2, N, M);

    dim3 grid(M / 64, N / 128);      // 64 x 64 = 4096 blocks, 4 waves each
    matern_main_kernel<<<grid, 256, 0, stream>>>(Xh, Xl, Zh, Zl, x2, z2, sig, len, out, M);
}